// Round 1
// baseline (1632.399 us; speedup 1.0000x reference)
//
#include <hip/hip_runtime.h>

// Problem constants
#define K 256
#define D 128
#define HW 1024          // H*W
#define CHW 131072       // D*HW (per-batch stride of z)
#define N_TOT 131072     // B*H*W
#define NELEM 16777216   // N_TOT * D

// Workspace layout (float indices)
#define WS_C2 0
#define WS_ENCSUM 256
#define WS_ENCB 512
#define WS_LOSS 33280
#define WS_FLAGCNT 33281
#define WS_LIST 33282
#define FLAG_CAP 16384

// Output layout (float indices, outputs concatenated in return order)
#define OUT_Q 0
#define OUT_IDX 16777216
#define OUT_COMMIT 16908288
#define OUT_CBLOSS 16908289
#define OUT_NEWCB 16908290
#define OUT_NEWCNT 16941058
#define OUT_NEWW 16941314

#define TAU 3e-4f

// ---------------------------------------------------------------------------
// Kernel 1: zero accumulators; compute c2[k] with numpy pairwise-8 order
// ---------------------------------------------------------------------------
__global__ void k_prep(const float* __restrict__ cb, float* __restrict__ ws) {
    int blk = blockIdx.x, tid = threadIdx.x;
    if (blk < 130) {
        int i = blk * 256 + tid;
        int cnt = WS_LIST - WS_ENCSUM;  // 33026 words: encsum, encbatch, loss, flagcnt
        if (i < cnt) ws[WS_ENCSUM + i] = 0.0f;
    } else {
        #pragma clang fp contract(off)
        int k = tid;  // 256 threads, one codebook row each
        const float* row = cb + (size_t)k * D;
        float r[8];
        #pragma unroll
        for (int j = 0; j < 8; ++j) r[j] = row[j] * row[j];
        for (int i = 8; i < D; i += 8) {
            #pragma unroll
            for (int j = 0; j < 8; ++j) r[j] = r[j] + row[i + j] * row[i + j];
        }
        ws[WS_C2 + k] = ((r[0] + r[1]) + (r[2] + r[3])) + ((r[4] + r[5]) + (r[6] + r[7]));
    }
}

// ---------------------------------------------------------------------------
// Kernel 2: main scoring. One thread per n. z row cached in 128 VGPRs.
// Phase-1 fp32 score s_k = z.c_k - 0.5*c2[k]; argmax == argmin of distance.
// Near-ties (gap < TAU) deferred to exact fallback kernel.
// ---------------------------------------------------------------------------
__global__ void __launch_bounds__(256, 2)
k_main(const float* __restrict__ z, const float* __restrict__ cb,
       float* __restrict__ ws, float* __restrict__ out) {
    const int tid = threadIdx.x;
    const int n = blockIdx.x * 256 + tid;
    const int b = n >> 10;
    const int hw = n & 1023;
    const float* zp = z + (size_t)b * CHW + hw;

    float zr[D];
    #pragma unroll
    for (int d = 0; d < D; ++d) zr[d] = zp[(size_t)d * HW];

    const float* __restrict__ c2s = ws + WS_C2;
    float best = -3.4e38f, second = -3.4e38f;
    int bk = 0;

    #pragma unroll 1
    for (int k = 0; k < K; k += 2) {
        const float* __restrict__ r0 = cb + (size_t)k * D;
        const float* __restrict__ r1 = r0 + D;
        float a00 = -0.5f * c2s[k], a01 = 0.f, a02 = 0.f, a03 = 0.f;
        float a10 = -0.5f * c2s[k + 1], a11 = 0.f, a12 = 0.f, a13 = 0.f;
        #pragma unroll
        for (int d = 0; d < D; d += 4) {
            a00 = fmaf(zr[d + 0], r0[d + 0], a00);
            a01 = fmaf(zr[d + 1], r0[d + 1], a01);
            a02 = fmaf(zr[d + 2], r0[d + 2], a02);
            a03 = fmaf(zr[d + 3], r0[d + 3], a03);
            a10 = fmaf(zr[d + 0], r1[d + 0], a10);
            a11 = fmaf(zr[d + 1], r1[d + 1], a11);
            a12 = fmaf(zr[d + 2], r1[d + 2], a12);
            a13 = fmaf(zr[d + 3], r1[d + 3], a13);
        }
        float s0 = (a00 + a01) + (a02 + a03);
        float s1 = (a10 + a11) + (a12 + a13);
        if (s0 > best) { second = best; best = s0; bk = k; }
        else if (s0 > second) second = s0;
        if (s1 > best) { second = best; best = s1; bk = k + 1; }
        else if (s1 > second) second = s1;
    }

    // Near-tie? defer this n entirely to the exact fallback kernel.
    bool flagged = (best - second) < TAU;
    if (flagged) {
        int slot = atomicAdd((int*)ws + WS_FLAGCNT, 1);
        if (slot < FLAG_CAP) ((int*)ws)[WS_LIST + slot] = n;
        else flagged = false;  // overflow: fall through to normal path
    }

    float lsum = 0.0f;
    if (!flagged) {
        out[OUT_IDX + n] = (float)bk;
        const float4* __restrict__ qrow = reinterpret_cast<const float4*>(cb + (size_t)bk * D);
        float* outp = out + OUT_Q + (size_t)b * CHW + hw;
        #pragma unroll
        for (int d4 = 0; d4 < D / 4; ++d4) {
            float4 q4 = qrow[d4];
            float qs[4] = {q4.x, q4.y, q4.z, q4.w};
            #pragma unroll
            for (int j = 0; j < 4; ++j) {
                int d = d4 * 4 + j;
                float q = qs[j];
                // straight-through: z + (q - z), matching reference fp rounding
                outp[(size_t)d * HW] = zr[d] + (q - zr[d]);
                float t = zr[d] - q;
                lsum = fmaf(t, t, lsum);
            }
        }
        // EMA scatter
        float* eb = ws + WS_ENCB + (size_t)bk * D;
        #pragma unroll
        for (int d = 0; d < D; ++d) atomicAdd(eb + d, zr[d]);
        atomicAdd(ws + WS_ENCSUM + bk, 1.0f);
    }

    // wave-level loss reduction, one atomic per wave
    #pragma unroll
    for (int off = 32; off >= 1; off >>= 1) lsum += __shfl_down(lsum, off);
    if ((tid & 63) == 0) atomicAdd(ws + WS_LOSS, lsum);
}

// ---------------------------------------------------------------------------
// Kernel 3: exact fallback for flagged n's. One block (256 threads) per n.
// Replicates the numpy fp32 pipeline: z2/c2 pairwise-8, zc via fp64 -> fp32,
// d = (z2 - 2*zc) + c2 with per-op fp32 rounding, argmin first-index.
// ---------------------------------------------------------------------------
__global__ void k_fallback(const float* __restrict__ z, const float* __restrict__ cb,
                           float* __restrict__ ws, float* __restrict__ out) {
    #pragma clang fp contract(off)
    const int tid = threadIdx.x;
    __shared__ float zs[D];
    __shared__ float z2s;
    __shared__ float dvals[K];
    __shared__ int kidx[K];

    int cnt = ((const int*)ws)[WS_FLAGCNT];
    if (cnt > FLAG_CAP) cnt = FLAG_CAP;

    for (int li = blockIdx.x; li < cnt; li += gridDim.x) {
        const int n = ((const int*)ws)[WS_LIST + li];
        const int b = n >> 10;
        const int hw = n & 1023;

        if (tid < D) zs[tid] = z[(size_t)b * CHW + (size_t)tid * HW + hw];
        __syncthreads();

        if (tid == 0) {
            float r[8];
            #pragma unroll
            for (int j = 0; j < 8; ++j) r[j] = zs[j] * zs[j];
            for (int i = 8; i < D; i += 8) {
                #pragma unroll
                for (int j = 0; j < 8; ++j) r[j] = r[j] + zs[i + j] * zs[i + j];
            }
            z2s = ((r[0] + r[1]) + (r[2] + r[3])) + ((r[4] + r[5]) + (r[6] + r[7]));
        }
        __syncthreads();

        // thread = candidate k
        {
            const float* row = cb + (size_t)tid * D;
            double acc = 0.0;
            for (int d = 0; d < D; ++d) acc += (double)zs[d] * (double)row[d];
            float zc = (float)acc;
            float dq = (z2s - 2.0f * zc) + ws[WS_C2 + tid];
            dvals[tid] = dq;
            kidx[tid] = tid;
        }
        __syncthreads();

        // first-min argmin reduction
        for (int s = K / 2; s > 0; s >>= 1) {
            if (tid < s) {
                float ov = dvals[tid + s]; int ok = kidx[tid + s];
                float mv = dvals[tid];     int mk = kidx[tid];
                if (ov < mv || (ov == mv && ok < mk)) { dvals[tid] = ov; kidx[tid] = ok; }
            }
            __syncthreads();
        }
        const int bk = kidx[0];
        __syncthreads();  // everyone has bk; dvals free for reuse

        float t2 = 0.0f;
        if (tid == 0) {
            out[OUT_IDX + n] = (float)bk;
            atomicAdd(ws + WS_ENCSUM + bk, 1.0f);
        }
        if (tid < D) {
            float q = cb[(size_t)bk * D + tid];
            out[OUT_Q + (size_t)b * CHW + (size_t)tid * HW + hw] = zs[tid] + (q - zs[tid]);
            float t = zs[tid] - q;
            t2 = t * t;
            atomicAdd(ws + WS_ENCB + (size_t)bk * D + tid, zs[tid]);
        }
        dvals[tid] = t2;
        __syncthreads();
        for (int s = K / 2; s > 0; s >>= 1) {
            if (tid < s) dvals[tid] += dvals[tid + s];
            __syncthreads();
        }
        if (tid == 0) atomicAdd(ws + WS_LOSS, dvals[0]);
        __syncthreads();  // protect shared reuse on next iteration
    }
}

// ---------------------------------------------------------------------------
// Kernel 4: finalize EMA outputs + losses. One block of 256 threads.
// ---------------------------------------------------------------------------
__global__ void k_finalize(const float* __restrict__ ema_count,
                           const float* __restrict__ ema_weight,
                           const float* __restrict__ ws, float* __restrict__ out) {
    #pragma clang fp contract(off)
    const int tid = threadIdx.x;
    __shared__ float red[K];
    __shared__ float normc[K];

    const float DEC = 0.99f;
    const float OMD = (float)(1.0 - 0.99);

    float nc = DEC * ema_count[tid] + OMD * ws[WS_ENCSUM + tid];
    out[OUT_NEWCNT + tid] = nc;
    red[tid] = nc;
    __syncthreads();
    for (int s = K / 2; s > 0; s >>= 1) {
        if (tid < s) red[tid] += red[tid + s];
        __syncthreads();
    }
    const float nt = red[0];
    normc[tid] = (nc + 1e-5f) / (nt + 0.00256f) * nt;
    __syncthreads();

    for (int i = tid; i < K * D; i += 256) {
        int k = i >> 7;
        float nw = DEC * ema_weight[i] + OMD * ws[WS_ENCB + i];
        out[OUT_NEWW + i] = nw;
        out[OUT_NEWCB + i] = nw / normc[k];
    }
    if (tid == 0) {
        float m = ws[WS_LOSS] / 16777216.0f;
        out[OUT_CBLOSS] = m;
        out[OUT_COMMIT] = 0.25f * m;
    }
}

// ---------------------------------------------------------------------------
extern "C" void kernel_launch(void* const* d_in, const int* in_sizes, int n_in,
                              void* d_out, int out_size, void* d_ws, size_t ws_size,
                              hipStream_t stream) {
    const float* z = (const float*)d_in[0];
    const float* cb = (const float*)d_in[1];
    const float* ema_count = (const float*)d_in[2];
    const float* ema_weight = (const float*)d_in[3];
    float* out = (float*)d_out;
    float* ws = (float*)d_ws;

    k_prep<<<131, 256, 0, stream>>>(cb, ws);
    k_main<<<N_TOT / 256, 256, 0, stream>>>(z, cb, ws, out);
    k_fallback<<<1024, 256, 0, stream>>>(z, cb, ws, out);
    k_finalize<<<1, 256, 0, stream>>>(ema_count, ema_weight, ws, out);
}

// Round 2
// 1415.958 us; speedup vs baseline: 1.1529x; 1.1529x over previous
//
#include <hip/hip_runtime.h>

// Problem constants
#define K 256
#define D 128
#define HW 1024          // H*W
#define CHW 131072       // D*HW (per-batch stride of z)
#define N_TOT 131072     // B*H*W
#define NELEM 16777216   // N_TOT * D

// Workspace layout (float indices)
#define WS_C2 0
#define WS_ENCSUM 256
#define WS_ENCB 512
#define WS_LOSS 33280
#define WS_FLAGCNT 33281
#define WS_LIST 33282
#define FLAG_CAP 16384

// Output layout (float indices, outputs concatenated in return order)
#define OUT_Q 0
#define OUT_IDX 16777216
#define OUT_COMMIT 16908288
#define OUT_CBLOSS 16908289
#define OUT_NEWCB 16908290
#define OUT_NEWCNT 16941058
#define OUT_NEWW 16941314

#define TAU 3e-4f
#define MT 64            // n-tile per block

// ---------------------------------------------------------------------------
// Kernel 1: zero accumulators; compute c2[k] with numpy pairwise-8 order
// ---------------------------------------------------------------------------
__global__ void k_prep(const float* __restrict__ cb, float* __restrict__ ws) {
    int blk = blockIdx.x, tid = threadIdx.x;
    if (blk < 130) {
        int i = blk * 256 + tid;
        int cnt = WS_LIST - WS_ENCSUM;  // 33026 words: encsum, encbatch, loss, flagcnt
        if (i < cnt) ws[WS_ENCSUM + i] = 0.0f;
    } else {
        #pragma clang fp contract(off)
        int k = tid;  // 256 threads, one codebook row each
        const float* row = cb + (size_t)k * D;
        float r[8];
        #pragma unroll
        for (int j = 0; j < 8; ++j) r[j] = row[j] * row[j];
        for (int i = 8; i < D; i += 8) {
            #pragma unroll
            for (int j = 0; j < 8; ++j) r[j] = r[j] + row[i + j] * row[i + j];
        }
        ws[WS_C2 + k] = ((r[0] + r[1]) + (r[2] + r[3])) + ((r[4] + r[5]) + (r[6] + r[7]));
    }
}

// ---------------------------------------------------------------------------
// Kernel 2: LDS-tiled GEMM-argmax. Block = 64 n x 256 k (4 k-tiles of 64).
// Thread (tx = t&15, ty = t>>4): 4 n's (tx*4..) x 4 k's (ty*4..) register acc.
// zs[d][n] transposed (conflict-free); cs XOR-swizzled k-tile.
// Phase-1 score s = z.c - 0.5*c2; near-ties (gap < TAU) -> exact fallback.
// ---------------------------------------------------------------------------
__global__ void __launch_bounds__(256, 2)
k_main(const float* __restrict__ z, const float* __restrict__ cb,
       float* __restrict__ ws, float* __restrict__ out) {
    __shared__ float zs[D * MT];       // zs[d][n], 32 KB
    __shared__ float cs[64 * D];       // k-tile, XOR-swizzled, 32 KB

    const int t = threadIdx.x;
    const int blk = blockIdx.x;
    const int n0 = blk * MT;
    const int b = n0 >> 10;
    const int hw0 = n0 & 1023;
    const float* __restrict__ zb = z + (size_t)b * CHW + hw0;

    // --- stage z tile: zs[d][nl], coalesced global, conflict-free LDS ---
    {
        const int nl = t & 63, dp = t >> 6;
        #pragma unroll 8
        for (int i = 0; i < 32; ++i) {
            int d = dp * 32 + i;
            zs[d * MT + nl] = zb[(size_t)d * HW + nl];
        }
    }

    const int tx = t & 15, ty = t >> 4;
    float best[4], second[4];
    int bk[4];
    #pragma unroll
    for (int i = 0; i < 4; ++i) { best[i] = -3.4e38f; second[i] = -3.4e38f; bk[i] = 0; }

    const float* __restrict__ c2s = ws + WS_C2;
    const float4* __restrict__ cb4 = reinterpret_cast<const float4*>(cb);
    const float4* __restrict__ zs4 = reinterpret_cast<const float4*>(zs);
    float4* __restrict__ cs4w = reinterpret_cast<float4*>(cs);

    for (int kt = 0; kt < 4; ++kt) {
        __syncthreads();  // zs ready (kt=0); prev-tile cs reads done (kt>0)
        // stage cs tile: cs4[kl*32 + (d4 ^ (kl&7))] = cb row kt*64+kl
        #pragma unroll
        for (int i = 0; i < 8; ++i) {
            int f = i * 256 + t;
            int kl = f >> 5, d4 = f & 31;
            cs4w[kl * 32 + (d4 ^ (kl & 7))] = cb4[(size_t)(kt * 64 + kl) * 32 + d4];
        }
        __syncthreads();

        float acc[4][4];
        #pragma unroll
        for (int j = 0; j < 4; ++j) {
            float init = -0.5f * c2s[kt * 64 + ty * 4 + j];
            #pragma unroll
            for (int i = 0; i < 4; ++i) acc[i][j] = init;
        }

        #pragma unroll 4
        for (int d4 = 0; d4 < 32; ++d4) {
            float z_[4][4];   // z_[jj][i] : d = d4*4+jj, n = tx*4+i
            #pragma unroll
            for (int jj = 0; jj < 4; ++jj) {
                float4 v = zs4[(d4 * 4 + jj) * 16 + tx];
                z_[jj][0] = v.x; z_[jj][1] = v.y; z_[jj][2] = v.z; z_[jj][3] = v.w;
            }
            float c_[4][4];   // c_[j][jj] : k = ty*4+j, d = d4*4+jj
            #pragma unroll
            for (int j = 0; j < 4; ++j) {
                int kl = ty * 4 + j;
                float4 v = zs4 == nullptr ? float4{} : reinterpret_cast<const float4*>(cs)[kl * 32 + (d4 ^ (kl & 7))];
                c_[j][0] = v.x; c_[j][1] = v.y; c_[j][2] = v.z; c_[j][3] = v.w;
            }
            #pragma unroll
            for (int i = 0; i < 4; ++i)
                #pragma unroll
                for (int j = 0; j < 4; ++j)
                    #pragma unroll
                    for (int jj = 0; jj < 4; ++jj)
                        acc[i][j] = fmaf(z_[jj][i], c_[j][jj], acc[i][j]);
        }

        // fold tile into per-thread top-2 (k increasing: kt outer, j inner)
        #pragma unroll
        for (int j = 0; j < 4; ++j) {
            int kg = kt * 64 + ty * 4 + j;
            #pragma unroll
            for (int i = 0; i < 4; ++i) {
                float s = acc[i][j];
                if (s > best[i]) { second[i] = best[i]; best[i] = s; bk[i] = kg; }
                else if (s > second[i]) second[i] = s;
            }
        }
    }

    // --- merge top-2 across the 16 ty-threads per n (alias cs region) ---
    __syncthreads();
    float* mb = cs;                       // [64][16]
    float* ms = cs + 1024;                // [64][16]
    int*   mk = (int*)(cs + 2048);        // [64][16]
    int*   bkA = (int*)(cs + 3072);       // [64]
    #pragma unroll
    for (int i = 0; i < 4; ++i) {
        int nl = tx * 4 + i;
        mb[nl * 16 + ty] = best[i];
        ms[nl * 16 + ty] = second[i];
        mk[nl * 16 + ty] = bk[i];
    }
    __syncthreads();

    if (t < 64) {
        float B = -3.4e38f, S = -3.4e38f;
        int KB = 0;
        #pragma unroll 4
        for (int y = 0; y < 16; ++y) {
            float b_ = mb[t * 16 + y], s_ = ms[t * 16 + y];
            int k_ = mk[t * 16 + y];
            if (b_ > B) { S = fmaxf(B, s_); B = b_; KB = k_; }
            else { S = fmaxf(S, b_); }
        }
        bool fl = (B - S) < TAU;
        int n = n0 + t;
        if (fl) {
            int slot = atomicAdd((int*)ws + WS_FLAGCNT, 1);
            if (slot < FLAG_CAP) ((int*)ws)[WS_LIST + slot] = n;
            else fl = false;
        }
        if (!fl) {
            out[OUT_IDX + n] = (float)KB;
            atomicAdd(ws + WS_ENCSUM + KB, 1.0f);
            bkA[t] = KB;
        } else {
            bkA[t] = -1;
        }
    }
    __syncthreads();

    // --- epilogue: q write (coalesced over n), loss, EMA scatter ---
    const int nl = t & 63, dp = t >> 6;
    const int bkn = bkA[nl];
    float lsum = 0.0f;
    if (bkn >= 0) {
        const float* __restrict__ crow = cb + (size_t)bkn * D;
        float* __restrict__ op = out + OUT_Q + (size_t)b * CHW + hw0 + nl;
        float* __restrict__ eb = ws + WS_ENCB + (size_t)bkn * D;
        #pragma unroll 8
        for (int i = 0; i < 32; ++i) {
            int d = dp * 32 + i;
            float zv = zs[d * MT + nl];
            float q = crow[d];
            op[(size_t)d * HW] = zv + (q - zv);   // straight-through rounding
            float tdf = zv - q;
            lsum = fmaf(tdf, tdf, lsum);
            atomicAdd(eb + d, zv);
        }
    }
    #pragma unroll
    for (int off = 32; off >= 1; off >>= 1) lsum += __shfl_down(lsum, off);
    if ((t & 63) == 0) atomicAdd(ws + WS_LOSS, lsum);
}

// ---------------------------------------------------------------------------
// Kernel 3: exact fallback for flagged n's. One block (256 threads) per n.
// Replicates the numpy fp32 pipeline: z2/c2 pairwise-8, zc via fp64 -> fp32,
// d = (z2 - 2*zc) + c2 with per-op fp32 rounding, argmin first-index.
// ---------------------------------------------------------------------------
__global__ void k_fallback(const float* __restrict__ z, const float* __restrict__ cb,
                           float* __restrict__ ws, float* __restrict__ out) {
    #pragma clang fp contract(off)
    const int tid = threadIdx.x;
    __shared__ float zs[D];
    __shared__ float z2s;
    __shared__ float dvals[K];
    __shared__ int kidx[K];

    int cnt = ((const int*)ws)[WS_FLAGCNT];
    if (cnt > FLAG_CAP) cnt = FLAG_CAP;

    for (int li = blockIdx.x; li < cnt; li += gridDim.x) {
        const int n = ((const int*)ws)[WS_LIST + li];
        const int b = n >> 10;
        const int hw = n & 1023;

        if (tid < D) zs[tid] = z[(size_t)b * CHW + (size_t)tid * HW + hw];
        __syncthreads();

        if (tid == 0) {
            float r[8];
            #pragma unroll
            for (int j = 0; j < 8; ++j) r[j] = zs[j] * zs[j];
            for (int i = 8; i < D; i += 8) {
                #pragma unroll
                for (int j = 0; j < 8; ++j) r[j] = r[j] + zs[i + j] * zs[i + j];
            }
            z2s = ((r[0] + r[1]) + (r[2] + r[3])) + ((r[4] + r[5]) + (r[6] + r[7]));
        }
        __syncthreads();

        // thread = candidate k
        {
            const float* row = cb + (size_t)tid * D;
            double acc = 0.0;
            for (int d = 0; d < D; ++d) acc += (double)zs[d] * (double)row[d];
            float zc = (float)acc;
            float dq = (z2s - 2.0f * zc) + ws[WS_C2 + tid];
            dvals[tid] = dq;
            kidx[tid] = tid;
        }
        __syncthreads();

        // first-min argmin reduction
        for (int s = K / 2; s > 0; s >>= 1) {
            if (tid < s) {
                float ov = dvals[tid + s]; int ok = kidx[tid + s];
                float mv = dvals[tid];     int mk = kidx[tid];
                if (ov < mv || (ov == mv && ok < mk)) { dvals[tid] = ov; kidx[tid] = ok; }
            }
            __syncthreads();
        }
        const int bk = kidx[0];
        __syncthreads();  // everyone has bk; dvals free for reuse

        float t2 = 0.0f;
        if (tid == 0) {
            out[OUT_IDX + n] = (float)bk;
            atomicAdd(ws + WS_ENCSUM + bk, 1.0f);
        }
        if (tid < D) {
            float q = cb[(size_t)bk * D + tid];
            out[OUT_Q + (size_t)b * CHW + (size_t)tid * HW + hw] = zs[tid] + (q - zs[tid]);
            float t = zs[tid] - q;
            t2 = t * t;
            atomicAdd(ws + WS_ENCB + (size_t)bk * D + tid, zs[tid]);
        }
        dvals[tid] = t2;
        __syncthreads();
        for (int s = K / 2; s > 0; s >>= 1) {
            if (tid < s) dvals[tid] += dvals[tid + s];
            __syncthreads();
        }
        if (tid == 0) atomicAdd(ws + WS_LOSS, dvals[0]);
        __syncthreads();  // protect shared reuse on next iteration
    }
}

// ---------------------------------------------------------------------------
// Kernel 4: finalize EMA outputs + losses. One block of 256 threads.
// ---------------------------------------------------------------------------
__global__ void k_finalize(const float* __restrict__ ema_count,
                           const float* __restrict__ ema_weight,
                           const float* __restrict__ ws, float* __restrict__ out) {
    #pragma clang fp contract(off)
    const int tid = threadIdx.x;
    __shared__ float red[K];
    __shared__ float normc[K];

    const float DEC = 0.99f;
    const float OMD = (float)(1.0 - 0.99);

    float nc = DEC * ema_count[tid] + OMD * ws[WS_ENCSUM + tid];
    out[OUT_NEWCNT + tid] = nc;
    red[tid] = nc;
    __syncthreads();
    for (int s = K / 2; s > 0; s >>= 1) {
        if (tid < s) red[tid] += red[tid + s];
        __syncthreads();
    }
    const float nt = red[0];
    normc[tid] = (nc + 1e-5f) / (nt + 0.00256f) * nt;
    __syncthreads();

    for (int i = tid; i < K * D; i += 256) {
        int k = i >> 7;
        float nw = DEC * ema_weight[i] + OMD * ws[WS_ENCB + i];
        out[OUT_NEWW + i] = nw;
        out[OUT_NEWCB + i] = nw / normc[k];
    }
    if (tid == 0) {
        float m = ws[WS_LOSS] / 16777216.0f;
        out[OUT_CBLOSS] = m;
        out[OUT_COMMIT] = 0.25f * m;
    }
}

// ---------------------------------------------------------------------------
extern "C" void kernel_launch(void* const* d_in, const int* in_sizes, int n_in,
                              void* d_out, int out_size, void* d_ws, size_t ws_size,
                              hipStream_t stream) {
    const float* z = (const float*)d_in[0];
    const float* cb = (const float*)d_in[1];
    const float* ema_count = (const float*)d_in[2];
    const float* ema_weight = (const float*)d_in[3];
    float* out = (float*)d_out;
    float* ws = (float*)d_ws;

    k_prep<<<131, 256, 0, stream>>>(cb, ws);
    k_main<<<N_TOT / MT, 256, 0, stream>>>(z, cb, ws, out);
    k_fallback<<<1024, 256, 0, stream>>>(z, cb, ws, out);
    k_finalize<<<1, 256, 0, stream>>>(ema_count, ema_weight, ws, out);
}

// Round 3
// 757.491 us; speedup vs baseline: 2.1550x; 1.8693x over previous
//
#include <hip/hip_runtime.h>

// Problem constants
#define K 256
#define D 128
#define HW 1024          // H*W
#define CHW 131072       // D*HW (per-batch stride of z)
#define N_TOT 131072     // B*H*W
#define NELEM 16777216   // N_TOT * D

// Workspace layout (float indices)
#define WS_C2 0
#define WS_ENCSUM 256
#define WS_ENCB 512
#define WS_LOSS 33280
#define WS_FLAGCNT 33281
#define WS_LIST 33282
#define FLAG_CAP 16384
#define WS_PART 49666            // 64 partial copies of (K*D + K)
#define PBLK 64
#define PSTRIDE 33024            // K*D + K
// total ws need: (49666 + 64*33024)*4 B = 8.65 MB

// Output layout (float indices, outputs concatenated in return order)
#define OUT_Q 0
#define OUT_IDX 16777216
#define OUT_COMMIT 16908288
#define OUT_CBLOSS 16908289
#define OUT_NEWCB 16908290
#define OUT_NEWCNT 16941058
#define OUT_NEWW 16941314

#define TAU 3e-4f
#define MT 64            // n-tile per block in k_main

// ---------------------------------------------------------------------------
// Kernel 1: zero loss/flagcnt; compute c2[k] with numpy pairwise-8 order
// ---------------------------------------------------------------------------
__global__ void k_prep(const float* __restrict__ cb, float* __restrict__ ws) {
    #pragma clang fp contract(off)
    int k = threadIdx.x;  // 256 threads, one codebook row each
    if (k == 0) { ws[WS_LOSS] = 0.0f; ((int*)ws)[WS_FLAGCNT] = 0; }
    const float* row = cb + (size_t)k * D;
    float r[8];
    #pragma unroll
    for (int j = 0; j < 8; ++j) r[j] = row[j] * row[j];
    for (int i = 8; i < D; i += 8) {
        #pragma unroll
        for (int j = 0; j < 8; ++j) r[j] = r[j] + row[i + j] * row[i + j];
    }
    ws[WS_C2 + k] = ((r[0] + r[1]) + (r[2] + r[3])) + ((r[4] + r[5]) + (r[6] + r[7]));
}

// ---------------------------------------------------------------------------
// Kernel 2: LDS-tiled GEMM-argmax. Block = 64 n x 256 k (4 k-tiles of 64).
// Thread (tx = t&15, ty = t>>4): 4 n's x 4 k's register acc.
// NO global atomics here — EMA stats are gathered later from idx.
// ---------------------------------------------------------------------------
__global__ void __launch_bounds__(256, 2)
k_main(const float* __restrict__ z, const float* __restrict__ cb,
       float* __restrict__ ws, float* __restrict__ out) {
    __shared__ float zs[D * MT];       // zs[d][n], 32 KB
    __shared__ float cs[64 * D];       // k-tile, XOR-swizzled, 32 KB

    const int t = threadIdx.x;
    const int blk = blockIdx.x;
    const int n0 = blk * MT;
    const int b = n0 >> 10;
    const int hw0 = n0 & 1023;
    const float* __restrict__ zb = z + (size_t)b * CHW + hw0;

    // --- stage z tile: zs[d][nl], coalesced global, conflict-free LDS ---
    {
        const int nl = t & 63, dp = t >> 6;
        #pragma unroll 8
        for (int i = 0; i < 32; ++i) {
            int d = dp * 32 + i;
            zs[d * MT + nl] = zb[(size_t)d * HW + nl];
        }
    }

    const int tx = t & 15, ty = t >> 4;
    float best[4], second[4];
    int bk[4];
    #pragma unroll
    for (int i = 0; i < 4; ++i) { best[i] = -3.4e38f; second[i] = -3.4e38f; bk[i] = 0; }

    const float* __restrict__ c2s = ws + WS_C2;
    const float4* __restrict__ cb4 = reinterpret_cast<const float4*>(cb);
    const float4* __restrict__ zs4 = reinterpret_cast<const float4*>(zs);
    const float4* __restrict__ cs4 = reinterpret_cast<const float4*>(cs);
    float4* __restrict__ cs4w = reinterpret_cast<float4*>(cs);

    for (int kt = 0; kt < 4; ++kt) {
        __syncthreads();  // zs ready (kt=0); prev-tile cs reads done (kt>0)
        // stage cs tile: cs4[kl*32 + (d4 ^ (kl&7))] = cb row kt*64+kl
        #pragma unroll
        for (int i = 0; i < 8; ++i) {
            int f = i * 256 + t;
            int kl = f >> 5, d4 = f & 31;
            cs4w[kl * 32 + (d4 ^ (kl & 7))] = cb4[(size_t)(kt * 64 + kl) * 32 + d4];
        }
        __syncthreads();

        float acc[4][4];
        #pragma unroll
        for (int j = 0; j < 4; ++j) {
            float init = -0.5f * c2s[kt * 64 + ty * 4 + j];
            #pragma unroll
            for (int i = 0; i < 4; ++i) acc[i][j] = init;
        }

        #pragma unroll 4
        for (int d4 = 0; d4 < 32; ++d4) {
            float z_[4][4];   // z_[jj][i] : d = d4*4+jj, n = tx*4+i
            #pragma unroll
            for (int jj = 0; jj < 4; ++jj) {
                float4 v = zs4[(d4 * 4 + jj) * 16 + tx];
                z_[jj][0] = v.x; z_[jj][1] = v.y; z_[jj][2] = v.z; z_[jj][3] = v.w;
            }
            float c_[4][4];   // c_[j][jj] : k = ty*4+j, d = d4*4+jj
            #pragma unroll
            for (int j = 0; j < 4; ++j) {
                int kl = ty * 4 + j;
                float4 v = cs4[kl * 32 + (d4 ^ (kl & 7))];
                c_[j][0] = v.x; c_[j][1] = v.y; c_[j][2] = v.z; c_[j][3] = v.w;
            }
            #pragma unroll
            for (int i = 0; i < 4; ++i)
                #pragma unroll
                for (int j = 0; j < 4; ++j)
                    #pragma unroll
                    for (int jj = 0; jj < 4; ++jj)
                        acc[i][j] = fmaf(z_[jj][i], c_[j][jj], acc[i][j]);
        }

        // fold tile into per-thread top-2 (k increasing: kt outer, j inner)
        #pragma unroll
        for (int j = 0; j < 4; ++j) {
            int kg = kt * 64 + ty * 4 + j;
            #pragma unroll
            for (int i = 0; i < 4; ++i) {
                float s = acc[i][j];
                if (s > best[i]) { second[i] = best[i]; best[i] = s; bk[i] = kg; }
                else if (s > second[i]) second[i] = s;
            }
        }
    }

    // --- merge top-2 across the 16 ty-threads per n (alias cs region) ---
    __syncthreads();
    float* mb = cs;                       // [64][16]
    float* ms = cs + 1024;                // [64][16]
    int*   mk = (int*)(cs + 2048);        // [64][16]
    int*   bkA = (int*)(cs + 3072);       // [64]
    #pragma unroll
    for (int i = 0; i < 4; ++i) {
        int nl = tx * 4 + i;
        mb[nl * 16 + ty] = best[i];
        ms[nl * 16 + ty] = second[i];
        mk[nl * 16 + ty] = bk[i];
    }
    __syncthreads();

    if (t < 64) {
        float B = -3.4e38f, S = -3.4e38f;
        int KB = 0;
        #pragma unroll 4
        for (int y = 0; y < 16; ++y) {
            float b_ = mb[t * 16 + y], s_ = ms[t * 16 + y];
            int k_ = mk[t * 16 + y];
            if (b_ > B) { S = fmaxf(B, s_); B = b_; KB = k_; }
            else { S = fmaxf(S, b_); }
        }
        bool fl = (B - S) < TAU;
        int n = n0 + t;
        if (fl) {
            int slot = atomicAdd((int*)ws + WS_FLAGCNT, 1);
            if (slot < FLAG_CAP) ((int*)ws)[WS_LIST + slot] = n;
            else fl = false;
        }
        if (!fl) {
            out[OUT_IDX + n] = (float)KB;
            bkA[t] = KB;
        } else {
            bkA[t] = -1;
        }
    }
    __syncthreads();

    // --- epilogue: q write (coalesced over n) + loss partial. No atomic scatter.
    const int nl = t & 63, dp = t >> 6;
    const int bkn = bkA[nl];
    float lsum = 0.0f;
    if (bkn >= 0) {
        const float* __restrict__ crow = cb + (size_t)bkn * D;
        float* __restrict__ op = out + OUT_Q + (size_t)b * CHW + hw0 + nl;
        #pragma unroll 8
        for (int i = 0; i < 32; ++i) {
            int d = dp * 32 + i;
            float zv = zs[d * MT + nl];
            float q = crow[d];
            op[(size_t)d * HW] = zv + (q - zv);   // straight-through rounding
            float tdf = zv - q;
            lsum = fmaf(tdf, tdf, lsum);
        }
    }
    #pragma unroll
    for (int off = 32; off >= 1; off >>= 1) lsum += __shfl_down(lsum, off);
    if ((t & 63) == 0) atomicAdd(ws + WS_LOSS, lsum);
}

// ---------------------------------------------------------------------------
// Kernel 3: exact fallback for flagged n's (numpy-bitwise distance pipeline).
// Writes idx/q/loss only — EMA stats come from the gather kernel.
// ---------------------------------------------------------------------------
__global__ void k_fallback(const float* __restrict__ z, const float* __restrict__ cb,
                           float* __restrict__ ws, float* __restrict__ out) {
    #pragma clang fp contract(off)
    const int tid = threadIdx.x;
    __shared__ float zs[D];
    __shared__ float z2s;
    __shared__ float dvals[K];
    __shared__ int kidx[K];

    int cnt = ((const int*)ws)[WS_FLAGCNT];
    if (cnt > FLAG_CAP) cnt = FLAG_CAP;

    for (int li = blockIdx.x; li < cnt; li += gridDim.x) {
        const int n = ((const int*)ws)[WS_LIST + li];
        const int b = n >> 10;
        const int hw = n & 1023;

        if (tid < D) zs[tid] = z[(size_t)b * CHW + (size_t)tid * HW + hw];
        __syncthreads();

        if (tid == 0) {
            float r[8];
            #pragma unroll
            for (int j = 0; j < 8; ++j) r[j] = zs[j] * zs[j];
            for (int i = 8; i < D; i += 8) {
                #pragma unroll
                for (int j = 0; j < 8; ++j) r[j] = r[j] + zs[i + j] * zs[i + j];
            }
            z2s = ((r[0] + r[1]) + (r[2] + r[3])) + ((r[4] + r[5]) + (r[6] + r[7]));
        }
        __syncthreads();

        // thread = candidate k
        {
            const float* row = cb + (size_t)tid * D;
            double acc = 0.0;
            for (int d = 0; d < D; ++d) acc += (double)zs[d] * (double)row[d];
            float zc = (float)acc;
            float dq = (z2s - 2.0f * zc) + ws[WS_C2 + tid];
            dvals[tid] = dq;
            kidx[tid] = tid;
        }
        __syncthreads();

        // first-min argmin reduction
        for (int s = K / 2; s > 0; s >>= 1) {
            if (tid < s) {
                float ov = dvals[tid + s]; int ok = kidx[tid + s];
                float mv = dvals[tid];     int mk = kidx[tid];
                if (ov < mv || (ov == mv && ok < mk)) { dvals[tid] = ov; kidx[tid] = ok; }
            }
            __syncthreads();
        }
        const int bk = kidx[0];
        __syncthreads();  // everyone has bk; dvals free for reuse

        float t2 = 0.0f;
        if (tid == 0) out[OUT_IDX + n] = (float)bk;
        if (tid < D) {
            float q = cb[(size_t)bk * D + tid];
            out[OUT_Q + (size_t)b * CHW + (size_t)tid * HW + hw] = zs[tid] + (q - zs[tid]);
            float t = zs[tid] - q;
            t2 = t * t;
        }
        dvals[tid] = t2;
        __syncthreads();
        for (int s = K / 2; s > 0; s >>= 1) {
            if (tid < s) dvals[tid] += dvals[tid + s];
            __syncthreads();
        }
        if (tid == 0) atomicAdd(ws + WS_LOSS, dvals[0]);
        __syncthreads();  // protect shared reuse on next iteration
    }
}

// ---------------------------------------------------------------------------
// Kernel 4: EMA gather. 64 blocks x 1024 threads; block = 2 batches.
// LDS-aggregated segment sum over idx (fire-and-forget ds_add, padded banks),
// partials to ws — zero global atomics.
// ---------------------------------------------------------------------------
__global__ void __launch_bounds__(1024)
k_emagather(const float* __restrict__ z, const float* __restrict__ out,
            float* __restrict__ ws) {
    __shared__ float accp[K * 33];     // padded [k][33] for one d-quarter, 33.8 KB
    __shared__ int   idxs[2048];       // 8 KB
    __shared__ float cnt[K];           // 1 KB

    const int t = threadIdx.x;
    const int blk = blockIdx.x;        // batches 2*blk, 2*blk+1

    if (t < K) cnt[t] = 0.0f;
    for (int j = t; j < 2048; j += 1024)
        idxs[j] = (int)out[OUT_IDX + (size_t)blk * 2048 + j];
    __syncthreads();
    for (int j = t; j < 2048; j += 1024)
        atomicAdd(&cnt[idxs[j]], 1.0f);

    const int dloc = t >> 5;           // 0..31
    const int li   = t & 31;
    float* __restrict__ pout = ws + WS_PART + (size_t)blk * PSTRIDE;

    for (int p = 0; p < 4; ++p) {
        for (int j = t; j < K * 33; j += 1024) accp[j] = 0.0f;
        __syncthreads();
        const int d = p * 32 + dloc;
        #pragma unroll
        for (int bb = 0; bb < 2; ++bb) {
            const float* __restrict__ zp = z + (size_t)(2 * blk + bb) * CHW + (size_t)d * HW;
            const int* __restrict__ ib = idxs + bb * 1024;
            #pragma unroll 4
            for (int i = 0; i < 32; ++i) {
                int hw = li + 32 * i;
                float v = zp[hw];
                int k = ib[hw];
                atomicAdd(&accp[k * 33 + dloc], v);   // LDS, no-return ds_add
            }
        }
        __syncthreads();
        for (int j = t; j < K * 32; j += 1024) {
            int k = j >> 5, dl = j & 31;
            pout[k * D + p * 32 + dl] = accp[k * 33 + dl];
        }
        __syncthreads();
    }
    if (t < K) pout[K * D + t] = cnt[t];
}

// ---------------------------------------------------------------------------
// Kernel 5: reduce 64 partial copies -> encbatch / encsum in ws
// ---------------------------------------------------------------------------
__global__ void k_emareduce(float* __restrict__ ws) {
    int e = blockIdx.x * 256 + threadIdx.x;
    if (e >= PSTRIDE) return;
    const float* __restrict__ p = ws + WS_PART + e;
    float s = 0.0f;
    #pragma unroll 8
    for (int g = 0; g < PBLK; ++g) s += p[(size_t)g * PSTRIDE];
    if (e < K * D) ws[WS_ENCB + e] = s;
    else ws[WS_ENCSUM + (e - K * D)] = s;
}

// ---------------------------------------------------------------------------
// Kernel 6: finalize EMA outputs + losses. One block of 256 threads.
// ---------------------------------------------------------------------------
__global__ void k_finalize(const float* __restrict__ ema_count,
                           const float* __restrict__ ema_weight,
                           const float* __restrict__ ws, float* __restrict__ out) {
    #pragma clang fp contract(off)
    const int tid = threadIdx.x;
    __shared__ float red[K];
    __shared__ float normc[K];

    const float DEC = 0.99f;
    const float OMD = (float)(1.0 - 0.99);

    float nc = DEC * ema_count[tid] + OMD * ws[WS_ENCSUM + tid];
    out[OUT_NEWCNT + tid] = nc;
    red[tid] = nc;
    __syncthreads();
    for (int s = K / 2; s > 0; s >>= 1) {
        if (tid < s) red[tid] += red[tid + s];
        __syncthreads();
    }
    const float nt = red[0];
    normc[tid] = (nc + 1e-5f) / (nt + 0.00256f) * nt;
    __syncthreads();

    for (int i = tid; i < K * D; i += 256) {
        int k = i >> 7;
        float nw = DEC * ema_weight[i] + OMD * ws[WS_ENCB + i];
        out[OUT_NEWW + i] = nw;
        out[OUT_NEWCB + i] = nw / normc[k];
    }
    if (tid == 0) {
        float m = ws[WS_LOSS] / 16777216.0f;
        out[OUT_CBLOSS] = m;
        out[OUT_COMMIT] = 0.25f * m;
    }
}

// ---------------------------------------------------------------------------
extern "C" void kernel_launch(void* const* d_in, const int* in_sizes, int n_in,
                              void* d_out, int out_size, void* d_ws, size_t ws_size,
                              hipStream_t stream) {
    const float* z = (const float*)d_in[0];
    const float* cb = (const float*)d_in[1];
    const float* ema_count = (const float*)d_in[2];
    const float* ema_weight = (const float*)d_in[3];
    float* out = (float*)d_out;
    float* ws = (float*)d_ws;

    k_prep<<<1, 256, 0, stream>>>(cb, ws);
    k_main<<<N_TOT / MT, 256, 0, stream>>>(z, cb, ws, out);
    k_fallback<<<1024, 256, 0, stream>>>(z, cb, ws, out);
    k_emagather<<<PBLK, 1024, 0, stream>>>(z, out, ws);
    k_emareduce<<<129, 256, 0, stream>>>(ws);
    k_finalize<<<1, 256, 0, stream>>>(ema_count, ema_weight, ws, out);
}

// Round 4
// 503.407 us; speedup vs baseline: 3.2427x; 1.5047x over previous
//
#include <hip/hip_runtime.h>

// Problem constants
#define K 256
#define D 128
#define HW 1024          // H*W
#define CHW 131072       // D*HW (per-batch stride of z)
#define N_TOT 131072     // B*H*W
#define NELEM 16777216   // N_TOT * D

// Workspace layout (float indices)
#define WS_C2 0
#define WS_ENCSUM 256
#define WS_ENCB 512
#define WS_LOSS 33280
#define WS_FLAGCNT 33281
#define WS_LIST 33282
#define FLAG_CAP 16384
#define WS_PART 49666            // 64 partial copies of (K*D + K)
#define PBLK 64
#define PSTRIDE 33024            // K*D + K
#define WS_CBT (WS_PART + PBLK * PSTRIDE)   // 2163202, cbT[d][k] 128x256
// total ws: (WS_CBT + 32768)*4 B = 8.78 MB

// Output layout (float indices, outputs concatenated in return order)
#define OUT_Q 0
#define OUT_IDX 16777216
#define OUT_COMMIT 16908288
#define OUT_CBLOSS 16908289
#define OUT_NEWCB 16908290
#define OUT_NEWCNT 16941058
#define OUT_NEWW 16941314

#define TAU 3e-4f
#define MT 128           // n-tile per block in k_main

// ---------------------------------------------------------------------------
// Kernel 1: zero loss/flagcnt; c2[k] with numpy pairwise-8 order; cbT[d][k]
// ---------------------------------------------------------------------------
__global__ void k_prep(const float* __restrict__ cb, float* __restrict__ ws) {
    #pragma clang fp contract(off)
    int k = threadIdx.x;  // 256 threads, one codebook row each
    if (k == 0) { ws[WS_LOSS] = 0.0f; ((int*)ws)[WS_FLAGCNT] = 0; }
    const float* row = cb + (size_t)k * D;
    float r[8];
    #pragma unroll
    for (int j = 0; j < 8; ++j) r[j] = row[j] * row[j];
    for (int i = 8; i < D; i += 8) {
        #pragma unroll
        for (int j = 0; j < 8; ++j) r[j] = r[j] + row[i + j] * row[i + j];
    }
    ws[WS_C2 + k] = ((r[0] + r[1]) + (r[2] + r[3])) + ((r[4] + r[5]) + (r[6] + r[7]));
    // transpose codebook: cbT[d][k]; lanes = k -> coalesced 1KB stores per d
    for (int d = 0; d < D; ++d) ws[WS_CBT + d * K + k] = row[d];
}

// ---------------------------------------------------------------------------
// Kernel 2: tiled GEMM-argmax. Block = 128 n x 256 k (2 k-tiles of 128).
// Thread (tx=t&15, ty=t>>4): 8 n's {4tx..+3, 64+4tx..+3} x 8 k's (same via ty).
// zs[d][n] (float4 over n), cs[d][k] (float4 over k, from pre-transposed cbT)
// -> conflict-free b128 reads, 1 B LDS per FMA. No global atomics.
// ---------------------------------------------------------------------------
__global__ void __launch_bounds__(256, 1)
k_main(const float* __restrict__ z, float* __restrict__ ws,
       float* __restrict__ out) {
    __shared__ float zs[D * MT];          // [d][n]  64 KB
    __shared__ float cs[D * 128];         // [d][k]  64 KB
    __shared__ float mb[MT * 17];         // merge best
    __shared__ float ms[MT * 17];         // merge second
    __shared__ int   mk[MT * 17];         // merge argbest
    __shared__ int   bkA[MT];

    const int t = threadIdx.x;
    const int blk = blockIdx.x;
    const int n0 = blk * MT;
    const int b = n0 >> 10;
    const int hw0 = n0 & 1023;

    const float4* __restrict__ z4 = reinterpret_cast<const float4*>(z);
    const float4* __restrict__ cbT4 = reinterpret_cast<const float4*>(ws + WS_CBT);
    const float4* __restrict__ zs4 = reinterpret_cast<const float4*>(zs);
    const float4* __restrict__ cs4 = reinterpret_cast<const float4*>(cs);
    float4* __restrict__ zs4w = reinterpret_cast<float4*>(zs);
    float4* __restrict__ cs4w = reinterpret_cast<float4*>(cs);
    const float* __restrict__ c2s = ws + WS_C2;

    // --- stage z tile: zs[d][n], coalesced 512B rows ---
    {
        const size_t zbase4 = (size_t)b * (CHW / 4) + (hw0 >> 2);
        #pragma unroll
        for (int i = 0; i < 16; ++i) {
            int f = i * 256 + t;
            int dd = f >> 5, n4 = f & 31;
            zs4w[dd * 32 + n4] = z4[zbase4 + (size_t)dd * (HW / 4) + n4];
        }
    }

    const int tx = t & 15, ty = t >> 4;
    float best[8], second[8];
    int bk[8];
    #pragma unroll
    for (int i = 0; i < 8; ++i) { best[i] = -3.4e38f; second[i] = -3.4e38f; bk[i] = 0; }

    for (int kt = 0; kt < 2; ++kt) {
        __syncthreads();   // zs ready (kt=0) / prior cs reads done (kt=1)
        #pragma unroll
        for (int i = 0; i < 16; ++i) {
            int f = i * 256 + t;
            int dd = f >> 5, k4 = f & 31;
            cs4w[dd * 32 + k4] = cbT4[(size_t)dd * 64 + kt * 32 + k4];
        }
        __syncthreads();

        float acc[8][8];
        #pragma unroll
        for (int j = 0; j < 8; ++j) {
            int kg = kt * 128 + (j >> 2) * 64 + 4 * ty + (j & 3);
            float init = -0.5f * c2s[kg];
            #pragma unroll
            for (int i = 0; i < 8; ++i) acc[i][j] = init;
        }

        #pragma unroll 2
        for (int d = 0; d < D; ++d) {
            float4 za = zs4[d * 32 + tx];
            float4 zb = zs4[d * 32 + tx + 16];
            float4 ca = cs4[d * 32 + ty];
            float4 cb2 = cs4[d * 32 + ty + 16];
            float az[8] = {za.x, za.y, za.z, za.w, zb.x, zb.y, zb.z, zb.w};
            float ak[8] = {ca.x, ca.y, ca.z, ca.w, cb2.x, cb2.y, cb2.z, cb2.w};
            #pragma unroll
            for (int i = 0; i < 8; ++i)
                #pragma unroll
                for (int j = 0; j < 8; ++j)
                    acc[i][j] = fmaf(az[i], ak[j], acc[i][j]);
        }

        // fold tile into per-thread top-2 (k increasing within thread)
        #pragma unroll
        for (int j = 0; j < 8; ++j) {
            int kg = kt * 128 + (j >> 2) * 64 + 4 * ty + (j & 3);
            #pragma unroll
            for (int i = 0; i < 8; ++i) {
                float s = acc[i][j];
                if (s > best[i]) { second[i] = best[i]; best[i] = s; bk[i] = kg; }
                else if (s > second[i]) second[i] = s;
            }
        }
    }

    __syncthreads();
    #pragma unroll
    for (int i = 0; i < 8; ++i) {
        int nl = (i >> 2) * 64 + 4 * tx + (i & 3);
        mb[nl * 17 + ty] = best[i];
        ms[nl * 17 + ty] = second[i];
        mk[nl * 17 + ty] = bk[i];
    }
    __syncthreads();

    if (t < MT) {
        float B = -3.4e38f, S = -3.4e38f;
        int KB = 0;
        #pragma unroll 4
        for (int y = 0; y < 16; ++y) {
            float b_ = mb[t * 17 + y], s_ = ms[t * 17 + y];
            int k_ = mk[t * 17 + y];
            if (b_ > B) { S = fmaxf(B, s_); B = b_; KB = k_; }
            else { S = fmaxf(S, b_); }
        }
        bool fl = (B - S) < TAU;
        int n = n0 + t;
        if (fl) {
            int slot = atomicAdd((int*)ws + WS_FLAGCNT, 1);
            if (slot < FLAG_CAP) ((int*)ws)[WS_LIST + slot] = n;
            else fl = false;
        }
        if (!fl) {
            out[OUT_IDX + n] = (float)KB;
            bkA[t] = KB;
        } else {
            bkA[t] = -1;
        }
    }
    __syncthreads();

    // --- epilogue: q write (coalesced over n) + loss partial ---
    // cs holds k-tile 128..255; rows 0..127 come from cbT gather (L2-hot).
    const int nl = t & 127, dp = t >> 7;
    const int bkn = bkA[nl];
    float lsum = 0.0f;
    if (bkn >= 0) {
        const float* __restrict__ ct = ws + WS_CBT;
        float* __restrict__ op = out + OUT_Q + (size_t)b * CHW + hw0 + nl;
        #pragma unroll 4
        for (int i = 0; i < 64; ++i) {
            int d = dp * 64 + i;
            float zv = zs[d * MT + nl];
            float q = ct[d * K + bkn];       // cbT[d][k] gather, cached
            op[(size_t)d * HW] = zv + (q - zv);   // straight-through rounding
            float tdf = zv - q;
            lsum = fmaf(tdf, tdf, lsum);
        }
    }
    #pragma unroll
    for (int off = 32; off >= 1; off >>= 1) lsum += __shfl_down(lsum, off);
    if ((t & 63) == 0) atomicAdd(ws + WS_LOSS, lsum);
}

// ---------------------------------------------------------------------------
// Kernel 3: exact fallback for flagged n's (numpy-bitwise distance pipeline).
// ---------------------------------------------------------------------------
__global__ void k_fallback(const float* __restrict__ z, const float* __restrict__ cb,
                           float* __restrict__ ws, float* __restrict__ out) {
    #pragma clang fp contract(off)
    const int tid = threadIdx.x;
    __shared__ float zs[D];
    __shared__ float z2s;
    __shared__ float dvals[K];
    __shared__ int kidx[K];

    int cnt = ((const int*)ws)[WS_FLAGCNT];
    if (cnt > FLAG_CAP) cnt = FLAG_CAP;

    for (int li = blockIdx.x; li < cnt; li += gridDim.x) {
        const int n = ((const int*)ws)[WS_LIST + li];
        const int b = n >> 10;
        const int hw = n & 1023;

        if (tid < D) zs[tid] = z[(size_t)b * CHW + (size_t)tid * HW + hw];
        __syncthreads();

        if (tid == 0) {
            float r[8];
            #pragma unroll
            for (int j = 0; j < 8; ++j) r[j] = zs[j] * zs[j];
            for (int i = 8; i < D; i += 8) {
                #pragma unroll
                for (int j = 0; j < 8; ++j) r[j] = r[j] + zs[i + j] * zs[i + j];
            }
            z2s = ((r[0] + r[1]) + (r[2] + r[3])) + ((r[4] + r[5]) + (r[6] + r[7]));
        }
        __syncthreads();

        {
            const float* row = cb + (size_t)tid * D;
            double acc = 0.0;
            for (int d = 0; d < D; ++d) acc += (double)zs[d] * (double)row[d];
            float zc = (float)acc;
            float dq = (z2s - 2.0f * zc) + ws[WS_C2 + tid];
            dvals[tid] = dq;
            kidx[tid] = tid;
        }
        __syncthreads();

        for (int s = K / 2; s > 0; s >>= 1) {
            if (tid < s) {
                float ov = dvals[tid + s]; int ok = kidx[tid + s];
                float mv = dvals[tid];     int mk2 = kidx[tid];
                if (ov < mv || (ov == mv && ok < mk2)) { dvals[tid] = ov; kidx[tid] = ok; }
            }
            __syncthreads();
        }
        const int bk = kidx[0];
        __syncthreads();

        float t2 = 0.0f;
        if (tid == 0) out[OUT_IDX + n] = (float)bk;
        if (tid < D) {
            float q = cb[(size_t)bk * D + tid];
            out[OUT_Q + (size_t)b * CHW + (size_t)tid * HW + hw] = zs[tid] + (q - zs[tid]);
            float t = zs[tid] - q;
            t2 = t * t;
        }
        dvals[tid] = t2;
        __syncthreads();
        for (int s = K / 2; s > 0; s >>= 1) {
            if (tid < s) dvals[tid] += dvals[tid + s];
            __syncthreads();
        }
        if (tid == 0) atomicAdd(ws + WS_LOSS, dvals[0]);
        __syncthreads();
    }
}

// ---------------------------------------------------------------------------
// Kernel 4: EMA gather, sort-based — NO accumulation atomics.
// 64 blocks x 1024 threads; block = 2 batches (2048 n). Counting-sort n by k
// in LDS, then lane (k,d) walks its bucket with plain ds_read + register acc.
// ---------------------------------------------------------------------------
#define GN 2048
#define ZSTR 2052        // 512 float4 + 4: bank = (4*dl + n) & 31
__global__ void __launch_bounds__(1024, 1)
k_emagather(const float* __restrict__ z, const float* __restrict__ out,
            float* __restrict__ ws) {
    __shared__ float zs[16 * ZSTR];    // 16-d chunk x 2048 n, 131.3 KB
    __shared__ int idxs[GN];           // 8 KB
    __shared__ int order[GN];          // 8 KB
    __shared__ int cnt[K];
    __shared__ int incl[K];
    __shared__ int startk[K];
    __shared__ int fill[K];

    const int t = threadIdx.x;
    const int blk = blockIdx.x;        // batches 2*blk, 2*blk+1

    for (int j = t; j < GN; j += 1024)
        idxs[j] = (int)out[OUT_IDX + (size_t)blk * GN + j];
    if (t < K) cnt[t] = 0;
    __syncthreads();
    for (int j = t; j < GN; j += 1024) atomicAdd(&cnt[idxs[j]], 1);
    __syncthreads();
    if (t < K) incl[t] = cnt[t];
    __syncthreads();
    for (int off = 1; off < K; off <<= 1) {
        int v = 0;
        if (t < K) { v = incl[t]; if (t >= off) v += incl[t - off]; }
        __syncthreads();
        if (t < K) incl[t] = v;
        __syncthreads();
    }
    if (t < K) { startk[t] = incl[t] - cnt[t]; fill[t] = incl[t] - cnt[t]; }
    __syncthreads();
    for (int j = t; j < GN; j += 1024) {
        int k = idxs[j];
        int p = atomicAdd(&fill[k], 1);
        order[p] = j;
    }
    float* __restrict__ pout = ws + WS_PART + (size_t)blk * PSTRIDE;
    if (t < K) pout[K * D + t] = (float)cnt[t];

    const float4* __restrict__ z4 = reinterpret_cast<const float4*>(z);
    const int dl = t & 15;
    const int k0 = (t >> 4) * 4;       // 4 k's per thread

    for (int p = 0; p < 8; ++p) {
        __syncthreads();               // protect zs reuse
        // stage zs[d2][n] for d = p*16+d2, n = bb*1024+hw
        for (int j = t; j < 16 * 512; j += 1024) {
            int d2 = j >> 9, n4 = j & 511;
            int bb = n4 >> 8, hw4 = n4 & 255;
            float4 v = z4[(size_t)(2 * blk + bb) * (CHW / 4)
                          + (size_t)(p * 16 + d2) * (HW / 4) + hw4];
            *reinterpret_cast<float4*>(&zs[d2 * ZSTR + 4 * n4]) = v;
        }
        __syncthreads();

        const float* __restrict__ zrow = zs + dl * ZSTR;
        #pragma unroll
        for (int kk = 0; kk < 4; ++kk) {
            int k = k0 + kk;
            int s = startk[k], e = s + cnt[k];
            float a = 0.0f;
            for (int q = s; q < e; ++q) a += zrow[order[q]];
            pout[(size_t)k * D + p * 16 + dl] = a;
        }
    }
}

// ---------------------------------------------------------------------------
// Kernel 5: reduce 64 partial copies -> encbatch / encsum in ws
// ---------------------------------------------------------------------------
__global__ void k_emareduce(float* __restrict__ ws) {
    int e = blockIdx.x * 256 + threadIdx.x;
    if (e >= PSTRIDE) return;
    const float* __restrict__ p = ws + WS_PART + e;
    float s = 0.0f;
    #pragma unroll 8
    for (int g = 0; g < PBLK; ++g) s += p[(size_t)g * PSTRIDE];
    if (e < K * D) ws[WS_ENCB + e] = s;
    else ws[WS_ENCSUM + (e - K * D)] = s;
}

// ---------------------------------------------------------------------------
// Kernel 6: finalize EMA outputs + losses. One block of 256 threads.
// ---------------------------------------------------------------------------
__global__ void k_finalize(const float* __restrict__ ema_count,
                           const float* __restrict__ ema_weight,
                           const float* __restrict__ ws, float* __restrict__ out) {
    #pragma clang fp contract(off)
    const int tid = threadIdx.x;
    __shared__ float red[K];
    __shared__ float normc[K];

    const float DEC = 0.99f;
    const float OMD = (float)(1.0 - 0.99);

    float nc = DEC * ema_count[tid] + OMD * ws[WS_ENCSUM + tid];
    out[OUT_NEWCNT + tid] = nc;
    red[tid] = nc;
    __syncthreads();
    for (int s = K / 2; s > 0; s >>= 1) {
        if (tid < s) red[tid] += red[tid + s];
        __syncthreads();
    }
    const float nt = red[0];
    normc[tid] = (nc + 1e-5f) / (nt + 0.00256f) * nt;
    __syncthreads();

    for (int i = tid; i < K * D; i += 256) {
        int k = i >> 7;
        float nw = DEC * ema_weight[i] + OMD * ws[WS_ENCB + i];
        out[OUT_NEWW + i] = nw;
        out[OUT_NEWCB + i] = nw / normc[k];
    }
    if (tid == 0) {
        float m = ws[WS_LOSS] / 16777216.0f;
        out[OUT_CBLOSS] = m;
        out[OUT_COMMIT] = 0.25f * m;
    }
}

// ---------------------------------------------------------------------------
extern "C" void kernel_launch(void* const* d_in, const int* in_sizes, int n_in,
                              void* d_out, int out_size, void* d_ws, size_t ws_size,
                              hipStream_t stream) {
    const float* z = (const float*)d_in[0];
    const float* cb = (const float*)d_in[1];
    const float* ema_count = (const float*)d_in[2];
    const float* ema_weight = (const float*)d_in[3];
    float* out = (float*)d_out;
    float* ws = (float*)d_ws;

    k_prep<<<1, 256, 0, stream>>>(cb, ws);
    k_main<<<N_TOT / MT, 256, 0, stream>>>(z, ws, out);
    k_fallback<<<1024, 256, 0, stream>>>(z, cb, ws, out);
    k_emagather<<<PBLK, 1024, 0, stream>>>(z, out, ws);
    k_emareduce<<<129, 256, 0, stream>>>(ws);
    k_finalize<<<1, 256, 0, stream>>>(ema_count, ema_weight, ws, out);
}

// Round 5
// 394.306 us; speedup vs baseline: 4.1399x; 1.2767x over previous
//
#include <hip/hip_runtime.h>

// Problem constants
#define K 256
#define D 128
#define HW 1024          // H*W
#define CHW 131072       // D*HW (per-batch stride of z)
#define N_TOT 131072     // B*H*W
#define NELEM 16777216   // N_TOT * D

// Workspace layout (float/dword indices)
#define WS_C2 0
#define WS_ENCSUM 256
#define WS_ENCB 512
#define WS_LOSS 33280
#define WS_FLAGCNT 33281
#define WS_LIST 33282
#define FLAG_CAP 16384
#define WS_PART 49666            // 64 partial copies of (K*D + K)
#define PBLK 64
#define PSTRIDE 33024            // K*D + K
#define WS_CBT (WS_PART + PBLK * PSTRIDE)   // 2163202, cbT[d][k] fp32
#define WS_CBH 2195972           // bf16-hi swizzled B frags, 16384 dwords (16B aligned)
#define WS_CBL 2212356           // bf16-lo swizzled B frags, 16384 dwords
// total ws: 2228740*4 B = 8.91 MB

// Output layout (float indices, outputs concatenated in return order)
#define OUT_Q 0
#define OUT_IDX 16777216
#define OUT_COMMIT 16908288
#define OUT_CBLOSS 16908289
#define OUT_NEWCB 16908290
#define OUT_NEWCNT 16941058
#define OUT_NEWW 16941314

#define TAU 3e-4f
#define MT 128           // n-tile per block in k_main
#define ZST 132          // zs row stride (128 + 4 pad)

typedef __attribute__((ext_vector_type(8))) short short8;
typedef __attribute__((ext_vector_type(4))) float floatx4;

// Split x into truncated-bf16 hi and bf16 lo (hi exact-subtracted remainder).
__device__ __forceinline__ void cvt_split(const float* xv, short8* hi, short8* lo) {
    union U { uint32_t u[4]; short8 s; } H, L;
    #pragma unroll
    for (int p = 0; p < 4; ++p) {
        uint32_t u0 = __float_as_uint(xv[2 * p]);
        uint32_t u1 = __float_as_uint(xv[2 * p + 1]);
        H.u[p] = (u0 >> 16) | (u1 & 0xFFFF0000u);
        float h0 = __uint_as_float(u0 & 0xFFFF0000u);
        float h1 = __uint_as_float(u1 & 0xFFFF0000u);
        float l0 = xv[2 * p] - h0;
        float l1 = xv[2 * p + 1] - h1;
        L.u[p] = (__float_as_uint(l0) >> 16) | (__float_as_uint(l1) & 0xFFFF0000u);
    }
    *hi = H.s; *lo = L.s;
}

// ---------------------------------------------------------------------------
// Kernel 1: blk<128: cbT transpose row d=blk. blk==128: c2 (numpy pairwise-8)
// + zero loss/flag. blk>128: bf16 hi/lo split of cb into MFMA-B fragment
// order: frag f=(ds*16+ktg), lane holds code=ktg*16+(lane&15),
// d = ds*32 + (lane>>4)*8 + j, 8 bf16 = one dwordx4.
// ---------------------------------------------------------------------------
__global__ void k_prep(const float* __restrict__ cb, float* __restrict__ ws) {
    #pragma clang fp contract(off)
    const int blk = blockIdx.x, t = threadIdx.x;
    if (blk < 128) {
        ws[WS_CBT + blk * K + t] = cb[(size_t)t * D + blk];
    } else if (blk == 128) {
        int k = t;
        if (k == 0) { ws[WS_LOSS] = 0.0f; ((int*)ws)[WS_FLAGCNT] = 0; }
        const float* row = cb + (size_t)k * D;
        float r[8];
        #pragma unroll
        for (int j = 0; j < 8; ++j) r[j] = row[j] * row[j];
        for (int i = 8; i < D; i += 8) {
            #pragma unroll
            for (int j = 0; j < 8; ++j) r[j] = r[j] + row[i + j] * row[i + j];
        }
        ws[WS_C2 + k] = ((r[0] + r[1]) + (r[2] + r[3])) + ((r[4] + r[5]) + (r[6] + r[7]));
    } else {
        int e = (blk - 129) * 4 + (t >> 6);   // frag id 0..63
        int lane = t & 63;
        int ds = e >> 4, ktg = e & 15;
        int code = ktg * 16 + (lane & 15);
        int d0 = ds * 32 + (lane >> 4) * 8;
        float xv[8];
        #pragma unroll
        for (int j = 0; j < 8; ++j) xv[j] = cb[(size_t)code * D + d0 + j];
        short8 h, l;
        cvt_split(xv, &h, &l);
        union V { short8 s; uint4 u; } Hv, Lv;
        Hv.s = h; Lv.s = l;
        uint32_t* wsu = (uint32_t*)ws;
        reinterpret_cast<uint4*>(wsu + WS_CBH)[e * 64 + lane] = Hv.u;
        reinterpret_cast<uint4*>(wsu + WS_CBL)[e * 64 + lane] = Lv.u;
    }
}

// ---------------------------------------------------------------------------
// Kernel 2: MFMA GEMM-argmax. Block = 128 n; wave w owns 32-n strip
// (2 m-tiles of 16). Score S[n,k] = z.c - 0.5*c2 via bf16 split:
// zh*ch + zh*cl + zl*ch, fp32 MFMA accumulation. B frags direct from L2.
// Per-(n) top-2 tracked in-lane then merged across the 16 cols via shfl_xor.
// Near-ties (gap < TAU) -> exact fallback.
// ---------------------------------------------------------------------------
__global__ void __launch_bounds__(256, 2)
k_main(const float* __restrict__ z, float* __restrict__ ws,
       float* __restrict__ out) {
    __shared__ float zs[D * ZST];      // zs[d][n], 67.6 KB
    __shared__ int bkA[MT];

    const int t = threadIdx.x;
    const int blk = blockIdx.x;
    const int n0 = blk * MT;
    const int b = n0 >> 10;
    const int hw0 = n0 & 1023;

    // --- stage z tile: zs[d][n] via float4 over hw ---
    {
        const float4* __restrict__ z4 = reinterpret_cast<const float4*>(z);
        const size_t zbase4 = (size_t)b * (CHW / 4) + (hw0 >> 2);
        #pragma unroll
        for (int i = 0; i < 16; ++i) {
            int f = i * 256 + t;
            int dd = f >> 5, n4 = f & 31;
            float4 v = z4[zbase4 + (size_t)dd * (HW / 4) + n4];
            *reinterpret_cast<float4*>(&zs[dd * ZST + 4 * n4]) = v;
        }
    }
    __syncthreads();

    const int lane = t & 63, w = t >> 6;
    const int col = lane & 15, quad = lane >> 4;
    const int mbase = w * 32;

    // --- A fragments: convert once, hold in regs (2 mt x 4 dsteps, hi+lo) ---
    short8 Ah[2][4], Al[2][4];
    {
        const int rbase = quad * 8 * ZST + mbase + col;
        #pragma unroll
        for (int mt = 0; mt < 2; ++mt)
            #pragma unroll
            for (int ds = 0; ds < 4; ++ds) {
                float xv[8];
                #pragma unroll
                for (int j = 0; j < 8; ++j)
                    xv[j] = zs[rbase + (ds * 32 + j) * ZST + mt * 16];
                cvt_split(xv, &Ah[mt][ds], &Al[mt][ds]);
            }
    }

    const uint32_t* wsu = (const uint32_t*)ws;
    const uint4* __restrict__ bh4 = reinterpret_cast<const uint4*>(wsu + WS_CBH);
    const uint4* __restrict__ bl4 = reinterpret_cast<const uint4*>(wsu + WS_CBL);
    const float* __restrict__ c2s = ws + WS_C2;

    float best[2][4], second[2][4];
    int bk[2][4];
    #pragma unroll
    for (int mt = 0; mt < 2; ++mt)
        #pragma unroll
        for (int r = 0; r < 4; ++r) { best[mt][r] = -3.4e38f; second[mt][r] = -3.4e38f; bk[mt][r] = 0; }

    #pragma unroll
    for (int ch = 0; ch < 4; ++ch) {        // 64-code chunks
        floatx4 acc[2][4];
        #pragma unroll
        for (int kt = 0; kt < 4; ++kt) {
            float iv = -0.5f * c2s[ch * 64 + kt * 16 + col];
            #pragma unroll
            for (int mt = 0; mt < 2; ++mt) {
                acc[mt][kt][0] = iv; acc[mt][kt][1] = iv;
                acc[mt][kt][2] = iv; acc[mt][kt][3] = iv;
            }
        }
        #pragma unroll
        for (int ds = 0; ds < 4; ++ds) {
            short8 bh[4], bl[4];
            #pragma unroll
            for (int kt = 0; kt < 4; ++kt) {
                int fi = (ds * 16 + ch * 4 + kt) * 64 + lane;
                union V { uint4 u; short8 s; } X, Y;
                X.u = bh4[fi]; Y.u = bl4[fi];
                bh[kt] = X.s; bl[kt] = Y.s;
            }
            #pragma unroll
            for (int mt = 0; mt < 2; ++mt)
                #pragma unroll
                for (int kt = 0; kt < 4; ++kt) {
                    acc[mt][kt] = __builtin_amdgcn_mfma_f32_16x16x32_bf16(Ah[mt][ds], bh[kt], acc[mt][kt], 0, 0, 0);
                    acc[mt][kt] = __builtin_amdgcn_mfma_f32_16x16x32_bf16(Ah[mt][ds], bl[kt], acc[mt][kt], 0, 0, 0);
                    acc[mt][kt] = __builtin_amdgcn_mfma_f32_16x16x32_bf16(Al[mt][ds], bh[kt], acc[mt][kt], 0, 0, 0);
                }
        }
        // fold chunk into per-lane top-2
        #pragma unroll
        for (int mt = 0; mt < 2; ++mt)
            #pragma unroll
            for (int kt = 0; kt < 4; ++kt) {
                int kc = ch * 64 + kt * 16 + col;
                #pragma unroll
                for (int r = 0; r < 4; ++r) {
                    float s = acc[mt][kt][r];
                    if (s > best[mt][r]) { second[mt][r] = best[mt][r]; best[mt][r] = s; bk[mt][r] = kc; }
                    else if (s > second[mt][r]) second[mt][r] = s;
                }
            }
    }

    // --- merge top-2 across the 16 cols (lanes sharing a quad) ---
    #pragma unroll
    for (int off = 1; off < 16; off <<= 1) {
        #pragma unroll
        for (int mt = 0; mt < 2; ++mt)
            #pragma unroll
            for (int r = 0; r < 4; ++r) {
                float ob = __shfl_xor(best[mt][r], off);
                float os = __shfl_xor(second[mt][r], off);
                int ok = __shfl_xor(bk[mt][r], off);
                float nb = fmaxf(best[mt][r], ob);
                float ns = fmaxf(fminf(best[mt][r], ob), fmaxf(second[mt][r], os));
                bk[mt][r] = (ob > best[mt][r]) ? ok : bk[mt][r];
                best[mt][r] = nb; second[mt][r] = ns;
            }
    }

    if (col == 0) {
        #pragma unroll
        for (int mt = 0; mt < 2; ++mt)
            #pragma unroll
            for (int r = 0; r < 4; ++r) {
                int nl = mbase + mt * 16 + quad * 4 + r;
                int n = n0 + nl;
                int KB = bk[mt][r];
                bool fl = (best[mt][r] - second[mt][r]) < TAU;
                if (fl) {
                    int slot = atomicAdd((int*)ws + WS_FLAGCNT, 1);
                    if (slot < FLAG_CAP) ((int*)ws)[WS_LIST + slot] = n;
                    else fl = false;
                }
                if (!fl) { out[OUT_IDX + n] = (float)KB; bkA[nl] = KB; }
                else bkA[nl] = -1;
            }
    }
    __syncthreads();

    // --- epilogue: q write (coalesced over n) + loss partial ---
    const int nl = t & 127, dp = t >> 7;
    const int bkn = bkA[nl];
    float lsum = 0.0f;
    if (bkn >= 0) {
        const float* __restrict__ ct = ws + WS_CBT;
        float* __restrict__ op = out + OUT_Q + (size_t)b * CHW + hw0 + nl;
        #pragma unroll 4
        for (int i = 0; i < 64; ++i) {
            int d = dp * 64 + i;
            float zv = zs[d * ZST + nl];
            float q = ct[d * K + bkn];            // cbT[d][k] gather, L2-hot
            op[(size_t)d * HW] = zv + (q - zv);   // straight-through rounding
            float tdf = zv - q;
            lsum = fmaf(tdf, tdf, lsum);
        }
    }
    #pragma unroll
    for (int off = 32; off >= 1; off >>= 1) lsum += __shfl_down(lsum, off);
    if ((t & 63) == 0) atomicAdd(ws + WS_LOSS, lsum);
}

// ---------------------------------------------------------------------------
// Kernel 3: exact fallback for flagged n's (numpy-bitwise distance pipeline).
// ---------------------------------------------------------------------------
__global__ void k_fallback(const float* __restrict__ z, const float* __restrict__ cb,
                           float* __restrict__ ws, float* __restrict__ out) {
    #pragma clang fp contract(off)
    const int tid = threadIdx.x;
    __shared__ float zsF[D];
    __shared__ float z2s;
    __shared__ float dvals[K];
    __shared__ int kidx[K];

    int cnt = ((const int*)ws)[WS_FLAGCNT];
    if (cnt > FLAG_CAP) cnt = FLAG_CAP;

    for (int li = blockIdx.x; li < cnt; li += gridDim.x) {
        const int n = ((const int*)ws)[WS_LIST + li];
        const int b = n >> 10;
        const int hw = n & 1023;

        if (tid < D) zsF[tid] = z[(size_t)b * CHW + (size_t)tid * HW + hw];
        __syncthreads();

        if (tid == 0) {
            float r[8];
            #pragma unroll
            for (int j = 0; j < 8; ++j) r[j] = zsF[j] * zsF[j];
            for (int i = 8; i < D; i += 8) {
                #pragma unroll
                for (int j = 0; j < 8; ++j) r[j] = r[j] + zsF[i + j] * zsF[i + j];
            }
            z2s = ((r[0] + r[1]) + (r[2] + r[3])) + ((r[4] + r[5]) + (r[6] + r[7]));
        }
        __syncthreads();

        {
            const float* row = cb + (size_t)tid * D;
            double acc = 0.0;
            for (int d = 0; d < D; ++d) acc += (double)zsF[d] * (double)row[d];
            float zc = (float)acc;
            float dq = (z2s - 2.0f * zc) + ws[WS_C2 + tid];
            dvals[tid] = dq;
            kidx[tid] = tid;
        }
        __syncthreads();

        for (int s = K / 2; s > 0; s >>= 1) {
            if (tid < s) {
                float ov = dvals[tid + s]; int ok = kidx[tid + s];
                float mv = dvals[tid];     int mk2 = kidx[tid];
                if (ov < mv || (ov == mv && ok < mk2)) { dvals[tid] = ov; kidx[tid] = ok; }
            }
            __syncthreads();
        }
        const int bk = kidx[0];
        __syncthreads();

        float t2 = 0.0f;
        if (tid == 0) out[OUT_IDX + n] = (float)bk;
        if (tid < D) {
            float q = cb[(size_t)bk * D + tid];
            out[OUT_Q + (size_t)b * CHW + (size_t)tid * HW + hw] = zsF[tid] + (q - zsF[tid]);
            float t = zsF[tid] - q;
            t2 = t * t;
        }
        dvals[tid] = t2;
        __syncthreads();
        for (int s = K / 2; s > 0; s >>= 1) {
            if (tid < s) dvals[tid] += dvals[tid + s];
            __syncthreads();
        }
        if (tid == 0) atomicAdd(ws + WS_LOSS, dvals[0]);
        __syncthreads();
    }
}

// ---------------------------------------------------------------------------
// Kernel 4: EMA gather, sort-based, NO accumulation atomics.
// 512 blocks x 1024 threads; block = (batch-pair p = blk>>3, d-chunk c = blk&7).
// Counting-sort n by k in LDS (redundant per chunk, cheap), then lane (k,d)
// walks its bucket with plain ds_read + register accumulate.
// ---------------------------------------------------------------------------
#define GN 2048
#define ZSTR 2052        // 512 float4 + 4
__global__ void __launch_bounds__(1024, 1)
k_emagather(const float* __restrict__ z, const float* __restrict__ out,
            float* __restrict__ ws) {
    __shared__ float zsg[16 * ZSTR];   // 16-d chunk x 2048 n, 131.3 KB
    __shared__ int idxs[GN];
    __shared__ int order[GN];
    __shared__ int cnt[K];
    __shared__ int incl[K];
    __shared__ int startk[K];
    __shared__ int fill[K];

    const int t = threadIdx.x;
    const int p = blockIdx.x >> 3;     // batch pair
    const int c = blockIdx.x & 7;      // d-chunk (16 d)

    for (int j = t; j < GN; j += 1024)
        idxs[j] = (int)out[OUT_IDX + (size_t)p * GN + j];
    if (t < K) cnt[t] = 0;
    __syncthreads();
    for (int j = t; j < GN; j += 1024) atomicAdd(&cnt[idxs[j]], 1);
    __syncthreads();
    if (t < K) incl[t] = cnt[t];
    __syncthreads();
    for (int off = 1; off < K; off <<= 1) {
        int v = 0;
        if (t < K) { v = incl[t]; if (t >= off) v += incl[t - off]; }
        __syncthreads();
        if (t < K) incl[t] = v;
        __syncthreads();
    }
    if (t < K) { startk[t] = incl[t] - cnt[t]; fill[t] = incl[t] - cnt[t]; }
    __syncthreads();
    for (int j = t; j < GN; j += 1024) {
        int k = idxs[j];
        int pos = atomicAdd(&fill[k], 1);
        order[pos] = j;
    }

    float* __restrict__ pout = ws + WS_PART + (size_t)p * PSTRIDE;
    if (c == 0 && t < K) pout[K * D + t] = (float)cnt[t];

    // stage zsg[d2][n] for d = c*16 + d2
    const float4* __restrict__ z4 = reinterpret_cast<const float4*>(z);
    for (int j = t; j < 16 * 512; j += 1024) {
        int d2 = j >> 9, n4 = j & 511;
        int bb = n4 >> 8, hw4 = n4 & 255;
        float4 v = z4[(size_t)(2 * p + bb) * (CHW / 4)
                      + (size_t)(c * 16 + d2) * (HW / 4) + hw4];
        *reinterpret_cast<float4*>(&zsg[d2 * ZSTR + 4 * n4]) = v;
    }
    __syncthreads();

    const int dl = t & 15;
    const int k0 = (t >> 4) * 4;       // 4 k's per thread
    const float* __restrict__ zrow = zsg + dl * ZSTR;
    #pragma unroll
    for (int kk = 0; kk < 4; ++kk) {
        int k = k0 + kk;
        int s = startk[k], e = s + cnt[k];
        float a = 0.0f;
        for (int q = s; q < e; ++q) a += zrow[order[q]];
        pout[(size_t)k * D + c * 16 + dl] = a;
    }
}

// ---------------------------------------------------------------------------
// Kernel 5: reduce 64 partial copies -> encbatch / encsum in ws
// ---------------------------------------------------------------------------
__global__ void k_emareduce(float* __restrict__ ws) {
    int e = blockIdx.x * 256 + threadIdx.x;
    if (e >= PSTRIDE) return;
    const float* __restrict__ p = ws + WS_PART + e;
    float s = 0.0f;
    #pragma unroll 8
    for (int g = 0; g < PBLK; ++g) s += p[(size_t)g * PSTRIDE];
    if (e < K * D) ws[WS_ENCB + e] = s;
    else ws[WS_ENCSUM + (e - K * D)] = s;
}

// ---------------------------------------------------------------------------
// Kernel 6: finalize EMA outputs + losses. One block of 256 threads.
// ---------------------------------------------------------------------------
__global__ void k_finalize(const float* __restrict__ ema_count,
                           const float* __restrict__ ema_weight,
                           const float* __restrict__ ws, float* __restrict__ out) {
    #pragma clang fp contract(off)
    const int tid = threadIdx.x;
    __shared__ float red[K];
    __shared__ float normc[K];

    const float DEC = 0.99f;
    const float OMD = (float)(1.0 - 0.99);

    float nc = DEC * ema_count[tid] + OMD * ws[WS_ENCSUM + tid];
    out[OUT_NEWCNT + tid] = nc;
    red[tid] = nc;
    __syncthreads();
    for (int s = K / 2; s > 0; s >>= 1) {
        if (tid < s) red[tid] += red[tid + s];
        __syncthreads();
    }
    const float nt = red[0];
    normc[tid] = (nc + 1e-5f) / (nt + 0.00256f) * nt;
    __syncthreads();

    for (int i = tid; i < K * D; i += 256) {
        int k = i >> 7;
        float nw = DEC * ema_weight[i] + OMD * ws[WS_ENCB + i];
        out[OUT_NEWW + i] = nw;
        out[OUT_NEWCB + i] = nw / normc[k];
    }
    if (tid == 0) {
        float m = ws[WS_LOSS] / 16777216.0f;
        out[OUT_CBLOSS] = m;
        out[OUT_COMMIT] = 0.25f * m;
    }
}

// ---------------------------------------------------------------------------
extern "C" void kernel_launch(void* const* d_in, const int* in_sizes, int n_in,
                              void* d_out, int out_size, void* d_ws, size_t ws_size,
                              hipStream_t stream) {
    const float* z = (const float*)d_in[0];
    const float* cb = (const float*)d_in[1];
    const float* ema_count = (const float*)d_in[2];
    const float* ema_weight = (const float*)d_in[3];
    float* out = (float*)d_out;
    float* ws = (float*)d_ws;

    k_prep<<<145, 256, 0, stream>>>(cb, ws);
    k_main<<<N_TOT / MT, 256, 0, stream>>>(z, ws, out);
    k_fallback<<<1024, 256, 0, stream>>>(z, cb, ws, out);
    k_emagather<<<512, 1024, 0, stream>>>(z, out, ws);
    k_emareduce<<<129, 256, 0, stream>>>(ws);
    k_finalize<<<1, 256, 0, stream>>>(ema_count, ema_weight, ws, out);
}